// Round 16
// baseline (54.149 us; speedup 1.0000x reference)
//
#include <hip/hip_runtime.h>

// Problem constants: B=8, N=2048, M=2048, D=128
#define B_DIM 8
#define N_DIM 2048
#define M_DIM 2048
#define D_DIM 128
#define NT_TILES 4

typedef __bf16 bf16_t;
typedef bf16_t bf16x8 __attribute__((ext_vector_type(8)));
typedef float f32x4 __attribute__((ext_vector_type(4)));
typedef float f32x16 __attribute__((ext_vector_type(16)));

// lgkm-only barrier: never drains vmcnt -> global stores / prefetch loads
// stay in flight across tile boundaries.
__device__ __forceinline__ void lgkm_barrier() {
    asm volatile("s_waitcnt lgkmcnt(0)" ::: "memory");
    __builtin_amdgcn_s_barrier();
}

// ---------------------------------------------------------------------------
// R11 (32x32x16 MFMA, full-line stores, fused staging, XCD-batch swizzle,
// lgkm-only barriers, prefetch-before-stores) + QUARTER-INTERLEAVED EPILOGUE:
//
// Old tile body: {32 MFMA (all 4 accs)} -> {64-output epilogue} -> {64 stores}
//   => every store depends on the tile's LAST MFMA; store issue is clumped
//   into ~25% of the wave timeline and the CU write pipe idles between
//   bursts (2 barrier-synced blocks/CU can't smooth it).
// New tile body: per tn half (2x): {8 dual-chain MFMAs for acc(tm=0),
//   acc(tm=1)} -> {epilogue + 32 stores}. Quarter q's stores have no dep on
//   quarter q+1's MFMAs => they drain UNDER the next MFMA chain. 4 store
//   windows per tile, <=2 live f32x16 accs (lower VGPR pressure).
// ---------------------------------------------------------------------------
__global__ __launch_bounds__(256, 2) void fused_dist_kernel(
    const float* __restrict__ L, const float* __restrict__ R,
    float* __restrict__ out)
{
    __shared__ bf16x8 Als[2048];   // 32 KB
    __shared__ bf16x8 Bls[2048];   // 32 KB
    __shared__ float nAs[128];
    __shared__ float nBs[128];

    // ---- XCD-locality decode: one batch per XCD (blockIdx round-robins XCDs)
    const int w   = blockIdx.x;    // [0, 512)
    const int bz  = w & 7;         // XCD id == batch
    const int i   = w >> 3;        // [0, 64) within XCD
    const int bxg = i & 3;         // covers NT_TILES bx tiles
    const int by  = i >> 2;        // [0, 16)

    const int tid  = threadIdx.x;
    const int wid  = tid >> 6;
    const int lane = tid & 63;
    const int rA   = lane & 15;        // row within 16-row LDS group
    const int g2   = (lane >> 4) & 1;  // which 16-row group within 32
    const int hi   = lane >> 5;        // 0..1 (K-half / row-offset select)
    const int c32  = lane & 31;        // fragment row/col within 32
    const int r    = tid >> 4;         // staging: row within 16-row group
    const int gran = tid & 15;         // staging: 8-elem chunk

    const float* Asrc = L + ((size_t)bz * N_DIM + (size_t)by * 128) * D_DIM;
    const float* Rbat = R + (size_t)bz * M_DIM * D_DIM;

    // ---- initial stage: A panel (bf16 RNE + norms from SAME rounded values)
    #pragma unroll
    for (int i2 = 0; i2 < 8; ++i2) {
        int row = i2 * 16 + r;
        float4 v0 = ((const float4*)Asrc)[(size_t)row * 32 + gran * 2];
        float4 v1 = ((const float4*)Asrc)[(size_t)row * 32 + gran * 2 + 1];
        bf16x8 p = { (bf16_t)v0.x, (bf16_t)v0.y, (bf16_t)v0.z, (bf16_t)v0.w,
                     (bf16_t)v1.x, (bf16_t)v1.y, (bf16_t)v1.z, (bf16_t)v1.w };
        Als[i2 * 256 + gran * 16 + (r ^ gran)] = p;
        float s = 0.0f;
        #pragma unroll
        for (int j = 0; j < 8; ++j) { float x = (float)p[j]; s = fmaf(x, x, s); }
        s += __shfl_xor(s, 1); s += __shfl_xor(s, 2);
        s += __shfl_xor(s, 4); s += __shfl_xor(s, 8);
        if (gran == 0) nAs[i2 * 16 + r] = s;
    }
    // ---- initial stage: B tile 0
    {
        const float* Bsrc = Rbat + (size_t)(bxg * NT_TILES) * 128 * D_DIM;
        #pragma unroll
        for (int i2 = 0; i2 < 8; ++i2) {
            int row = i2 * 16 + r;
            float4 v0 = ((const float4*)Bsrc)[(size_t)row * 32 + gran * 2];
            float4 v1 = ((const float4*)Bsrc)[(size_t)row * 32 + gran * 2 + 1];
            bf16x8 p = { (bf16_t)v0.x, (bf16_t)v0.y, (bf16_t)v0.z, (bf16_t)v0.w,
                         (bf16_t)v1.x, (bf16_t)v1.y, (bf16_t)v1.z, (bf16_t)v1.w };
            Bls[i2 * 256 + gran * 16 + (r ^ gran)] = p;
            float s = 0.0f;
            #pragma unroll
            for (int j = 0; j < 8; ++j) { float x = (float)p[j]; s = fmaf(x, x, s); }
            s += __shfl_xor(s, 1); s += __shfl_xor(s, 2);
            s += __shfl_xor(s, 4); s += __shfl_xor(s, 8);
            if (gran == 0) nBs[i2 * 16 + r] = s;
        }
    }
    lgkm_barrier();

    // ---- wave tile bases: each wave owns 64x64 = 2x2 of 32x32 MFMA tiles
    const int wM = (wid >> 1) * 64;
    const int wN = (wid & 1) * 64;

    // ---- A fragments into registers (Als dead afterwards): af[tm][s]
    bf16x8 af[2][8];
    #pragma unroll
    for (int s = 0; s < 8; ++s) {
        const int gr = s * 2 + hi;           // 16B k-granule
        #pragma unroll
        for (int tm = 0; tm < 2; ++tm) {
            const int grp = (wM >> 4) + tm * 2 + g2;
            af[tm][s] = Als[grp * 256 + gr * 16 + (rA ^ gr)];
        }
    }

    // ---- tile loop
    for (int t = 0; t < NT_TILES; ++t) {
        const int bx = bxg * NT_TILES + t;
        const size_t outBase =
            ((size_t)bz * N_DIM + (size_t)by * 128) * M_DIM + (size_t)bx * 128;
        float4 pf0[8], pf1[8];

        #pragma unroll
        for (int tn = 0; tn < 2; ++tn) {
            // 1. dual-chain MFMA for this tn half (acc for tm=0 and tm=1)
            f32x16 a0 = {}, a1 = {};
            #pragma unroll
            for (int s = 0; s < 8; ++s) {
                const int gr = s * 2 + hi;
                const int grp = (wN >> 4) + tn * 2 + g2;
                const bf16x8 bfr = Bls[grp * 256 + gr * 16 + (rA ^ gr)];
                a0 = __builtin_amdgcn_mfma_f32_32x32x16_bf16(af[0][s], bfr, a0, 0, 0, 0);
                a1 = __builtin_amdgcn_mfma_f32_32x32x16_bf16(af[1][s], bfr, a1, 0, 0, 0);
            }

            // 2. prefetch next B tile BEFORE the first store burst (vmcnt
            //    retires in-order: restage's wait stays counted, stores are
            //    never force-drained)
            if (tn == 0 && t + 1 < NT_TILES) {
                const float* Bsrc = Rbat + (size_t)(bx + 1) * 128 * D_DIM;
                #pragma unroll
                for (int i2 = 0; i2 < 8; ++i2) {
                    int row = i2 * 16 + r;
                    pf0[i2] = ((const float4*)Bsrc)[(size_t)row * 32 + gran * 2];
                    pf1[i2] = ((const float4*)Bsrc)[(size_t)row * 32 + gran * 2 + 1];
                }
            }

            // 3. epilogue + full-line stores for this tn half (32 outputs)
            //    out-row = wM + tm*32 + g*8 + hi*4 + e, out-col = wN+tn*32+c32
            const int col_l = wN + tn * 32 + c32;
            const float r2 = nBs[col_l];
            float* ocol = out + outBase + col_l;
            #pragma unroll
            for (int tm = 0; tm < 2; ++tm) {
                const f32x16 aq = tm ? a1 : a0;
                #pragma unroll
                for (int g = 0; g < 4; ++g) {
                    const int rowb = wM + tm * 32 + g * 8 + hi * 4;
                    const f32x4 l2q = *(const f32x4*)&nAs[rowb];
                    #pragma unroll
                    for (int e = 0; e < 4; ++e) {
                        float d2 = fmaf(-2.0f, aq[g * 4 + e], l2q[e] + r2);
                        d2 = fmaxf(d2, 0.0f);
                        float sq = __builtin_amdgcn_sqrtf(d2);
                        ocol[(size_t)(rowb + e) * M_DIM] =
                            __builtin_amdgcn_rcpf(1.0f + sq);
                    }
                }
            }
        }

        // 4. restage next B tile from prefetched regs (lgkm-only barriers)
        if (t + 1 < NT_TILES) {
            lgkm_barrier();                    // all waves done reading Bls/nBs
            #pragma unroll
            for (int i2 = 0; i2 < 8; ++i2) {
                bf16x8 p = { (bf16_t)pf0[i2].x, (bf16_t)pf0[i2].y,
                             (bf16_t)pf0[i2].z, (bf16_t)pf0[i2].w,
                             (bf16_t)pf1[i2].x, (bf16_t)pf1[i2].y,
                             (bf16_t)pf1[i2].z, (bf16_t)pf1[i2].w };
                Bls[i2 * 256 + gran * 16 + (r ^ gran)] = p;
                float s = 0.0f;
                #pragma unroll
                for (int j = 0; j < 8; ++j) { float x = (float)p[j]; s = fmaf(x, x, s); }
                s += __shfl_xor(s, 1); s += __shfl_xor(s, 2);
                s += __shfl_xor(s, 4); s += __shfl_xor(s, 8);
                if (gran == 0) nBs[i2 * 16 + r] = s;
            }
            lgkm_barrier();                    // staging visible
        }
    }
}

extern "C" void kernel_launch(void* const* d_in, const int* in_sizes, int n_in,
                              void* d_out, int out_size, void* d_ws, size_t ws_size,
                              hipStream_t stream) {
    const float* L = (const float*)d_in[0];
    const float* R = (const float*)d_in[1];
    float* out = (float*)d_out;

    // 1D grid: w&7 selects XCD (round-robin) == batch; 64 blocks per XCD.
    dim3 grid(512, 1, 1);
    dim3 block(256);
    fused_dist_kernel<<<grid, block, 0, stream>>>(L, R, out);
}

// Round 17
// 45.460 us; speedup vs baseline: 1.1911x; 1.1911x over previous
//
#include <hip/hip_runtime.h>

// Problem constants: B=8, N=2048, M=2048, D=128
#define B_DIM 8
#define N_DIM 2048
#define M_DIM 2048
#define D_DIM 128
#define NT_TILES 4

typedef __bf16 bf16_t;
typedef bf16_t bf16x8 __attribute__((ext_vector_type(8)));
typedef float f32x4 __attribute__((ext_vector_type(4)));
typedef float f32x16 __attribute__((ext_vector_type(16)));

// lgkm-only barrier: never drains vmcnt -> global stores / prefetch loads
// stay in flight across tile boundaries.
__device__ __forceinline__ void lgkm_barrier() {
    asm volatile("s_waitcnt lgkmcnt(0)" ::: "memory");
    __builtin_amdgcn_s_barrier();
}

// ---------------------------------------------------------------------------
// R11 champion (32x32x16 MFMA s-outer 4-acc, full-line stores, fused staging,
// XCD-batch swizzle, lgkm-only barriers, prefetch-before-stores) +
// DOUBLE-BUFFERED B VIA A-PANEL ALIASING:
//
// Champion's per-tile sync was {barrier -> ds_write Bls -> barrier}: two
// full-block rendezvous with the restage serialized between them (B single-
// buffered). All 512 blocks are co-resident => chip-wide lockstep pulses;
// the write pipe idles during every rendezvous window.
//
// A's 32KB LDS region is dead after the one-time af register load, so it
// becomes B's second buffer: tile t computes from region (t&1)^1 while the
// restage writes region (t&1). No reader/writer overlap => the pre-write
// barrier disappears; ONE rendezvous per tile, and each wave restages as
// soon as its prefetch lands. Full unroll => buffer index is compile-time.
// ---------------------------------------------------------------------------
__global__ __launch_bounds__(256, 2) void fused_dist_kernel(
    const float* __restrict__ L, const float* __restrict__ R,
    float* __restrict__ out)
{
    __shared__ bf16x8 ldsAB[4096];   // 64 KB: P0=[0,2048) A->B', P1=[2048,..) B
    __shared__ float nAs[128];
    __shared__ float nBsD[2][128];

    // ---- XCD-locality decode: one batch per XCD (blockIdx round-robins XCDs)
    const int w   = blockIdx.x;    // [0, 512)
    const int bz  = w & 7;         // XCD id == batch
    const int i   = w >> 3;        // [0, 64) within XCD
    const int bxg = i & 3;         // covers NT_TILES bx tiles
    const int by  = i >> 2;        // [0, 16)

    const int tid  = threadIdx.x;
    const int wid  = tid >> 6;
    const int lane = tid & 63;
    const int rA   = lane & 15;        // row within 16-row LDS group
    const int g2   = (lane >> 4) & 1;  // which 16-row group within 32
    const int hi   = lane >> 5;        // 0..1 (K-half / row-offset select)
    const int c32  = lane & 31;        // fragment row/col within 32
    const int r    = tid >> 4;         // staging: row within 16-row group
    const int gran = tid & 15;         // staging: 8-elem chunk

    const float* Asrc = L + ((size_t)bz * N_DIM + (size_t)by * 128) * D_DIM;
    const float* Rbat = R + (size_t)bz * M_DIM * D_DIM;

    // ---- initial stage: A panel -> P0 (bf16 RNE + norms from SAME values)
    #pragma unroll
    for (int i2 = 0; i2 < 8; ++i2) {
        int row = i2 * 16 + r;
        float4 v0 = ((const float4*)Asrc)[(size_t)row * 32 + gran * 2];
        float4 v1 = ((const float4*)Asrc)[(size_t)row * 32 + gran * 2 + 1];
        bf16x8 p = { (bf16_t)v0.x, (bf16_t)v0.y, (bf16_t)v0.z, (bf16_t)v0.w,
                     (bf16_t)v1.x, (bf16_t)v1.y, (bf16_t)v1.z, (bf16_t)v1.w };
        ldsAB[i2 * 256 + gran * 16 + (r ^ gran)] = p;
        float s = 0.0f;
        #pragma unroll
        for (int j = 0; j < 8; ++j) { float x = (float)p[j]; s = fmaf(x, x, s); }
        s += __shfl_xor(s, 1); s += __shfl_xor(s, 2);
        s += __shfl_xor(s, 4); s += __shfl_xor(s, 8);
        if (gran == 0) nAs[i2 * 16 + r] = s;
    }
    // ---- initial stage: B tile 0 -> P1
    {
        const float* Bsrc = Rbat + (size_t)(bxg * NT_TILES) * 128 * D_DIM;
        #pragma unroll
        for (int i2 = 0; i2 < 8; ++i2) {
            int row = i2 * 16 + r;
            float4 v0 = ((const float4*)Bsrc)[(size_t)row * 32 + gran * 2];
            float4 v1 = ((const float4*)Bsrc)[(size_t)row * 32 + gran * 2 + 1];
            bf16x8 p = { (bf16_t)v0.x, (bf16_t)v0.y, (bf16_t)v0.z, (bf16_t)v0.w,
                         (bf16_t)v1.x, (bf16_t)v1.y, (bf16_t)v1.z, (bf16_t)v1.w };
            ldsAB[2048 + i2 * 256 + gran * 16 + (r ^ gran)] = p;
            float s = 0.0f;
            #pragma unroll
            for (int j = 0; j < 8; ++j) { float x = (float)p[j]; s = fmaf(x, x, s); }
            s += __shfl_xor(s, 1); s += __shfl_xor(s, 2);
            s += __shfl_xor(s, 4); s += __shfl_xor(s, 8);
            if (gran == 0) nBsD[1][i2 * 16 + r] = s;
        }
    }
    lgkm_barrier();   // staging visible

    // ---- wave tile bases: each wave owns 64x64 = 2x2 of 32x32 MFMA tiles
    const int wM = (wid >> 1) * 64;
    const int wN = (wid & 1) * 64;

    // ---- A fragments into registers from P0: af[tm][s]
    bf16x8 af[2][8];
    #pragma unroll
    for (int s = 0; s < 8; ++s) {
        const int gr = s * 2 + hi;           // 16B k-granule
        #pragma unroll
        for (int tm = 0; tm < 2; ++tm) {
            const int grp = (wM >> 4) + tm * 2 + g2;
            af[tm][s] = ldsAB[grp * 256 + gr * 16 + (rA ^ gr)];
        }
    }
    lgkm_barrier();   // all af reads done: P0 may now be overwritten (tile 0)

    // ---- tile loop (fully unrolled: buffer indices compile-time)
    #pragma unroll
    for (int t = 0; t < NT_TILES; ++t) {
        const int cur = (t & 1) ^ 1;      // t0:P1, t1:P0, t2:P1, t3:P0
        const int nxt = t & 1;
        const bf16x8* Bcur = ldsAB + cur * 2048;
        const int bx = bxg * NT_TILES + t;

        // 1. MFMA on current B tile (8 K-steps, 4 independent acc chains)
        f32x16 acc[2][2] = {};
        #pragma unroll
        for (int s = 0; s < 8; ++s) {
            const int gr = s * 2 + hi;
            bf16x8 bfr[2];
            #pragma unroll
            for (int tn = 0; tn < 2; ++tn) {
                const int grp = (wN >> 4) + tn * 2 + g2;
                bfr[tn] = Bcur[grp * 256 + gr * 16 + (rA ^ gr)];
            }
            #pragma unroll
            for (int tm = 0; tm < 2; ++tm)
                #pragma unroll
                for (int tn = 0; tn < 2; ++tn)
                    acc[tm][tn] = __builtin_amdgcn_mfma_f32_32x32x16_bf16(
                        af[tm][s], bfr[tn], acc[tm][tn], 0, 0, 0);
        }

        // 2. prefetch next B tile (f32) into regs BEFORE any stores issue
        //    (vmcnt in-order: restage's wait stays counted, stores never
        //     force-drained)
        float4 pf0[8], pf1[8];
        if (t + 1 < NT_TILES) {
            const float* Bsrc = Rbat + (size_t)(bx + 1) * 128 * D_DIM;
            #pragma unroll
            for (int i2 = 0; i2 < 8; ++i2) {
                int row = i2 * 16 + r;
                pf0[i2] = ((const float4*)Bsrc)[(size_t)row * 32 + gran * 2];
                pf1[i2] = ((const float4*)Bsrc)[(size_t)row * 32 + gran * 2 + 1];
            }
        }

        // 3. epilogue + full-line stores
        //    out-row = wM + tm*32 + g*8 + hi*4 + e,  out-col = wN + tn*32 + c32
        const size_t outBase =
            ((size_t)bz * N_DIM + (size_t)by * 128) * M_DIM + (size_t)bx * 128;
        #pragma unroll
        for (int tm = 0; tm < 2; ++tm) {
            #pragma unroll
            for (int tn = 0; tn < 2; ++tn) {
                const int col_l = wN + tn * 32 + c32;
                const float r2 = nBsD[cur][col_l];
                float* ocol = out + outBase + col_l;
                #pragma unroll
                for (int g = 0; g < 4; ++g) {
                    const int rowb = wM + tm * 32 + g * 8 + hi * 4;
                    const f32x4 l2q = *(const f32x4*)&nAs[rowb];
                    #pragma unroll
                    for (int e = 0; e < 4; ++e) {
                        float d2 = fmaf(-2.0f, acc[tm][tn][g * 4 + e],
                                        l2q[e] + r2);
                        d2 = fmaxf(d2, 0.0f);
                        float sq = __builtin_amdgcn_sqrtf(d2);
                        ocol[(size_t)(rowb + e) * M_DIM] =
                            __builtin_amdgcn_rcpf(1.0f + sq);
                    }
                }
            }
        }

        // 4. restage next B tile into the OTHER region (no pre-write barrier:
        //    readers are on `cur`); ONE rendezvous per tile after the write.
        if (t + 1 < NT_TILES) {
            #pragma unroll
            for (int i2 = 0; i2 < 8; ++i2) {
                bf16x8 p = { (bf16_t)pf0[i2].x, (bf16_t)pf0[i2].y,
                             (bf16_t)pf0[i2].z, (bf16_t)pf0[i2].w,
                             (bf16_t)pf1[i2].x, (bf16_t)pf1[i2].y,
                             (bf16_t)pf1[i2].z, (bf16_t)pf1[i2].w };
                ldsAB[nxt * 2048 + i2 * 256 + gran * 16 + (r ^ gran)] = p;
                float s = 0.0f;
                #pragma unroll
                for (int j = 0; j < 8; ++j) { float x = (float)p[j]; s = fmaf(x, x, s); }
                s += __shfl_xor(s, 1); s += __shfl_xor(s, 2);
                s += __shfl_xor(s, 4); s += __shfl_xor(s, 8);
                if (gran == 0) nBsD[nxt][i2 * 16 + r] = s;
            }
            lgkm_barrier();    // staging visible; next tile reads `nxt`
        }
    }
}

extern "C" void kernel_launch(void* const* d_in, const int* in_sizes, int n_in,
                              void* d_out, int out_size, void* d_ws, size_t ws_size,
                              hipStream_t stream) {
    const float* L = (const float*)d_in[0];
    const float* R = (const float*)d_in[1];
    float* out = (float*)d_out;

    // 1D grid: w&7 selects XCD (round-robin) == batch; 64 blocks per XCD.
    dim3 grid(512, 1, 1);
    dim3 block(256);
    fused_dist_kernel<<<grid, block, 0, stream>>>(L, R, out);
}